// Round 3
// baseline (454.782 us; speedup 1.0000x reference)
//
#include <hip/hip_runtime.h>
#include <hip/hip_bf16.h>

// LSTM_single_task: B=32768, I=H=512. Live math: 3 gate GEMMs (i,c,o) over
// u=[x,h] (K=1024), fused activations. f-gate and c_prev are dead code.
//
// R2: DTYPE-ADAPTIVE. R0 (async staging) and R1 (explicit staging) both
// produced NaN -> staging acquitted; leading theory is the inputs are fp32
// (per the documented contract: reference dtype is float32) and reading them
// as bf16 yields ~0.8% NaN bit patterns. A device-side probe classifies the
// x buffer (low-u16 exponent-field sanity), and all kernels branch
// (wave-uniformly) between fp32 and bf16 I/O. Compute is bf16 MFMA either
// way (error ~0.008 << 0.0193 threshold).

typedef unsigned short u16;
typedef u16 u16x8 __attribute__((ext_vector_type(8)));
typedef __bf16 bf16x8 __attribute__((ext_vector_type(8)));
typedef float f32x4 __attribute__((ext_vector_type(4)));

#define B_DIM 32768
#define H_DIM 512
#define K_DIM 1024
#define BH_ELEMS (B_DIM * H_DIM)   // 16,777,216

__device__ __forceinline__ float bf2f(u16 u) {
    unsigned v = ((unsigned)u) << 16;
    float f;
    __builtin_memcpy(&f, &v, 4);
    return f;
}

__device__ __forceinline__ u16 f2bf16u(float f) {
    __hip_bfloat16 b = __float2bfloat16(f);   // RNE
    u16 u;
    __builtin_memcpy(&u, &b, 2);
    return u;
}

__device__ __forceinline__ float fast_sigmoid(float x) {
    return 1.0f / (1.0f + __expf(-x));
}

__device__ __forceinline__ float fast_tanh(float x) {
    float e = __expf(-2.0f * fabsf(x));     // in (0,1], never overflows
    float r = (1.0f - e) / (1.0f + e);
    return x < 0.0f ? -r : r;
}

// -------- probe: classify input storage dtype ------------------------------
// fp32 N(0,1) data: low u16 of each word ~ uniform -> bf16-exponent-field
// "sane" fraction ~16%. bf16 data: low u16 IS a bf16 value -> ~100% sane.
__global__ void probe_dtype(const unsigned* __restrict__ x, int* __restrict__ flag) {
    const int lane = threadIdx.x;
    const unsigned lo = x[lane] & 0xFFFFu;
    const unsigned e = (lo >> 7) & 0xFFu;
    const bool sane = (e >= 100u && e <= 140u) || (lo == 0u);
    const unsigned long long m = __ballot(sane);
    if (lane == 0) *flag = (__popcll(m) >= 48) ? 1 : 0;   // 1 = bf16, 0 = fp32
}

// -------- prep: pack W into Wt[g][n][k] (bf16), n-major, k = [Wx ; Wh] -----
// grid (16,16,6): z = gate*2 + half; 32x32 LDS transpose, block (32,8).
__global__ void pack_weights(const void* __restrict__ Wxi, const void* __restrict__ Whi,
                             const void* __restrict__ Wxc, const void* __restrict__ Whc,
                             const void* __restrict__ Wxo, const void* __restrict__ Who,
                             const int* __restrict__ flag, u16* __restrict__ Wt)
{
    __shared__ u16 tile[32][33];
    const bool isbf = (*flag != 0);
    const int g = blockIdx.z >> 1, half = blockIdx.z & 1;
    const void* src;
    if (g == 0)      src = half ? Whi : Wxi;
    else if (g == 1) src = half ? Whc : Wxc;
    else             src = half ? Who : Wxo;
    const int kk = blockIdx.y * 32, nn = blockIdx.x * 32;
    const int tx = threadIdx.x, ty = threadIdx.y;
    if (isbf) {
        const u16* s = (const u16*)src;
#pragma unroll
        for (int i2 = 0; i2 < 4; ++i2)
            tile[ty + 8 * i2][tx] = s[(kk + ty + 8 * i2) * 512 + nn + tx];
    } else {
        const float* s = (const float*)src;
#pragma unroll
        for (int i2 = 0; i2 < 4; ++i2)
            tile[ty + 8 * i2][tx] = f2bf16u(s[(kk + ty + 8 * i2) * 512 + nn + tx]);
    }
    __syncthreads();
#pragma unroll
    for (int i2 = 0; i2 < 4; ++i2)
        Wt[(long)g * 524288 + (long)(nn + ty + 8 * i2) * 1024 + half * 512 + kk + tx]
            = tile[tx][ty + 8 * i2];
}

// -------- main: fused 3-gate GEMM + activations ---------------------------
// grid (8, 256): x = n-tile (64 cols), y = m-tile (128 rows). 256 threads.
__global__ __launch_bounds__(256, 2) void lstm_gemm(
    const void* __restrict__ x, const void* __restrict__ h,
    const u16* __restrict__ Wt,
    const void* __restrict__ bxi, const void* __restrict__ bxc,
    const void* __restrict__ bxo, const int* __restrict__ flag,
    void* __restrict__ out)
{
    __shared__ __align__(16) u16 As[128 * 32];       // [row][k] row-major, 8 KB
    __shared__ __align__(16) u16 Bs[3 * 64 * 32];    // [g][n][k] row-major, 12 KB

    const bool isbf = (*flag != 0);
    const int tid    = threadIdx.x;
    const int lane   = tid & 63;
    const int wave   = tid >> 6;
    const int wave_m = wave & 1;       // 2x2 wave grid over 128x64
    const int wave_n = wave >> 1;
    const int m0 = blockIdx.y * 128;
    const int n0 = blockIdx.x * 64;

    // ---- explicit staging addresses (per-thread 16B(bf16)/32B(fp32) chunks) --
    const int trow = tid >> 2, tkc = (tid & 3) * 8;
    const long a_g0 = (long)(m0 + trow)      * 512 + tkc;
    const long a_g1 = (long)(m0 + 64 + trow) * 512 + tkc;
    const int  a_l0 = tid * 8;
    const int  a_l1 = 2048 + tid * 8;
    long b_g[3];
#pragma unroll
    for (int q = 0; q < 3; ++q)
        b_g[q] = (long)q * 524288 + (long)(n0 + trow) * 1024 + tkc;

    // ---- fragment LDS offsets (A/B operand: m/n = lane&15, k = (lane>>4)*8+j) --
    int a_ld[4];
#pragma unroll
    for (int mt = 0; mt < 4; ++mt)
        a_ld[mt] = (wave_m * 64 + mt * 16 + (lane & 15)) * 32 + (lane >> 4) * 8;
    int b_ld[3][2];
#pragma unroll
    for (int g = 0; g < 3; ++g)
#pragma unroll
        for (int nt = 0; nt < 2; ++nt)
            b_ld[g][nt] = g * 2048 + (wave_n * 32 + nt * 16 + (lane & 15)) * 32 + (lane >> 4) * 8;

    f32x4 acc[3][4][2];
    const f32x4 zero = {0.f, 0.f, 0.f, 0.f};
#pragma unroll
    for (int g = 0; g < 3; ++g)
#pragma unroll
        for (int mt = 0; mt < 4; ++mt)
#pragma unroll
            for (int nt = 0; nt < 2; ++nt)
                acc[g][mt][nt] = zero;

    // ---- K loop: u = [x, h] along k; Wt already holds full K=1024 ----------
    for (int k0 = 0; k0 < K_DIM; k0 += 32) {
        const void* src = (k0 < 512) ? x : h;
        const long kadj = (k0 < 512) ? k0 : (k0 - 512);

        bf16x8 av0, av1, bv[3];
        if (isbf) {
            const u16* s = (const u16*)src + kadj;
            u16x8 t0 = *(const u16x8*)(s + a_g0);
            u16x8 t1 = *(const u16x8*)(s + a_g1);
            __builtin_memcpy(&av0, &t0, 16);
            __builtin_memcpy(&av1, &t1, 16);
        } else {
            const float* s = (const float*)src + kadj;
            f32x4 p0 = *(const f32x4*)(s + a_g0);
            f32x4 p1 = *(const f32x4*)(s + a_g0 + 4);
            f32x4 q0 = *(const f32x4*)(s + a_g1);
            f32x4 q1 = *(const f32x4*)(s + a_g1 + 4);
#pragma unroll
            for (int j = 0; j < 4; ++j) {
                av0[j] = (__bf16)p0[j]; av0[4 + j] = (__bf16)p1[j];
                av1[j] = (__bf16)q0[j]; av1[4 + j] = (__bf16)q1[j];
            }
        }
#pragma unroll
        for (int q = 0; q < 3; ++q) {
            u16x8 t = *(const u16x8*)(Wt + b_g[q] + k0);
            __builtin_memcpy(&bv[q], &t, 16);
        }

        __syncthreads();   // previous iter's ds_reads done -> safe to overwrite
        *(bf16x8*)&As[a_l0] = av0;
        *(bf16x8*)&As[a_l1] = av1;
#pragma unroll
        for (int q = 0; q < 3; ++q)
            *(bf16x8*)&Bs[q * 2048 + tid * 8] = bv[q];
        __syncthreads();   // staged data visible to all waves

        bf16x8 af[4];
#pragma unroll
        for (int mt = 0; mt < 4; ++mt)
            af[mt] = *(const bf16x8*)&As[a_ld[mt]];
        bf16x8 bfr[3][2];
#pragma unroll
        for (int g = 0; g < 3; ++g)
#pragma unroll
            for (int nt = 0; nt < 2; ++nt)
                bfr[g][nt] = *(const bf16x8*)&Bs[b_ld[g][nt]];

#pragma unroll
        for (int g = 0; g < 3; ++g)
#pragma unroll
            for (int mt = 0; mt < 4; ++mt)
#pragma unroll
            for (int nt = 0; nt < 2; ++nt)
                acc[g][mt][nt] = __builtin_amdgcn_mfma_f32_16x16x32_bf16(
                    af[mt], bfr[g][nt], acc[g][mt][nt], 0, 0, 0);
    }

    // ---- epilogue: bias + activations + store (dtype-matched) ---------------
    // C/D layout: col = lane&15, row = (lane>>4)*4 + reg  [m89/m91 verified]
    const int colbase = n0 + wave_n * 32 + (lane & 15);
    float bi[2], bc[2], bo[2];
#pragma unroll
    for (int nt = 0; nt < 2; ++nt) {
        const int col = colbase + nt * 16;
        if (isbf) {
            bi[nt] = bf2f(((const u16*)bxi)[col]);
            bc[nt] = bf2f(((const u16*)bxc)[col]);
            bo[nt] = bf2f(((const u16*)bxo)[col]);
        } else {
            bi[nt] = ((const float*)bxi)[col];
            bc[nt] = ((const float*)bxc)[col];
            bo[nt] = ((const float*)bxo)[col];
        }
    }

    const int rowbase = m0 + wave_m * 64 + (lane >> 4) * 4;
#pragma unroll
    for (int mt = 0; mt < 4; ++mt)
#pragma unroll
        for (int nt = 0; nt < 2; ++nt)
#pragma unroll
            for (int r = 0; r < 4; ++r) {
                const int row = rowbase + mt * 16 + r;
                const int col = colbase + nt * 16;
                const float iv = fast_sigmoid(acc[0][mt][nt][r] + bi[nt]);
                const float cv = iv * fast_tanh(acc[1][mt][nt][r] + bc[nt]);
                const float ov = fast_sigmoid(acc[2][mt][nt][r] + bo[nt]);
                const float hv = ov * fast_tanh(cv);
                const long idx = (long)row * 512 + col;
                if (isbf) {
                    ((u16*)out)[idx]            = f2bf16u(hv);
                    ((u16*)out)[BH_ELEMS + idx] = f2bf16u(cv);
                } else {
                    ((float*)out)[idx]            = hv;
                    ((float*)out)[BH_ELEMS + idx] = cv;
                }
            }
}

extern "C" void kernel_launch(void* const* d_in, const int* in_sizes, int n_in,
                              void* d_out, int out_size, void* d_ws, size_t ws_size,
                              hipStream_t stream) {
    const void* x   = d_in[0];
    const void* h   = d_in[1];
    // d_in[2] = c_prev: dead in reference math, not read.
    const void* Wxi = d_in[3];
    const void* bxi = d_in[4];
    const void* Whi = d_in[5];
    // d_in[6..8] = Wxf/bxf/Whf: f gate is computed-then-discarded -> skipped.
    const void* Wxc = d_in[9];
    const void* bxc = d_in[10];
    const void* Whc = d_in[11];
    const void* Wxo = d_in[12];
    const void* bxo = d_in[13];
    const void* Who = d_in[14];

    int* flag = (int*)d_ws;                       // [0,4): dtype flag
    u16* Wt   = (u16*)((char*)d_ws + 256);        // 3 MB packed weights (bf16)

    probe_dtype<<<1, 64, 0, stream>>>((const unsigned*)x, flag);
    pack_weights<<<dim3(16, 16, 6), dim3(32, 8), 0, stream>>>(
        Wxi, Whi, Wxc, Whc, Wxo, Who, flag, Wt);
    lstm_gemm<<<dim3(8, 256), dim3(256), 0, stream>>>(
        x, h, Wt, bxi, bxc, bxo, flag, d_out);
}